// Round 1
// baseline (2082.330 us; speedup 1.0000x reference)
//
#include <hip/hip_runtime.h>
#include <stdint.h>

#define NN 50000   // nodes
#define NE 800000  // edges
#define HD 128     // hidden
#define NL 4       // layers

typedef __bf16 bf16x8 __attribute__((ext_vector_type(8)));
typedef float  f32x4  __attribute__((ext_vector_type(4)));

__device__ __forceinline__ f32x4 mfma16(bf16x8 a, bf16x8 b, f32x4 c) {
  return __builtin_amdgcn_mfma_f32_16x16x32_bf16(a, b, c, 0, 0, 0);
}

template<int MT, int NT>
__device__ __forceinline__ void zero_acc(f32x4 (&acc)[MT][NT]) {
#pragma unroll
  for (int i = 0; i < MT; ++i)
#pragma unroll
    for (int j = 0; j < NT; ++j) acc[i][j] = f32x4{0.f, 0.f, 0.f, 0.f};
}

// C[m][n] += A[m][k] * B[k][n], A in LDS (row-major, stride sa), B given
// TRANSPOSED in global (Bt[n][k], row stride K). Wave computes MT*16 x NT*16.
template<int MT, int NT, int K>
__device__ __forceinline__ void run_gemm(const __bf16* A, int sa,
    const __bf16* __restrict__ Bt, int m_off, int n_off, int lane,
    f32x4 (&acc)[MT][NT])
{
  const int arow = lane & 15;
  const int quad = lane >> 4;
#pragma unroll
  for (int ks = 0; ks < K / 32; ++ks) {
    const int k = ks * 32 + quad * 8;
    bf16x8 a[MT], b[NT];
#pragma unroll
    for (int mt = 0; mt < MT; ++mt)
      a[mt] = *reinterpret_cast<const bf16x8*>(A + (m_off + mt * 16 + arow) * sa + k);
#pragma unroll
    for (int nt = 0; nt < NT; ++nt)
      b[nt] = *reinterpret_cast<const bf16x8*>(Bt + (size_t)(n_off + nt * 16 + arow) * K + k);
#pragma unroll
    for (int mt = 0; mt < MT; ++mt)
#pragma unroll
      for (int nt = 0; nt < NT; ++nt)
        acc[mt][nt] = mfma16(a[mt], b[nt], acc[mt][nt]);
  }
}

// C/D layout (m89-verified): col = lane&15, row = (lane>>4)*4 + reg
template<int MT, int NT, bool RELU>
__device__ __forceinline__ void store_tile(__bf16* O, int so,
    const float* __restrict__ bias, int m_off, int n_off, int lane,
    f32x4 (&acc)[MT][NT])
{
  const int quad = lane >> 4;
  const int cl = lane & 15;
#pragma unroll
  for (int nt = 0; nt < NT; ++nt) {
    const int col = n_off + nt * 16 + cl;
    const float bv = bias[col];
#pragma unroll
    for (int mt = 0; mt < MT; ++mt)
#pragma unroll
      for (int r = 0; r < 4; ++r) {
        const int row = m_off + mt * 16 + quad * 4 + r;
        float v = acc[mt][nt][r] + bv;
        if (RELU) v = fmaxf(v, 0.f);
        O[row * so + col] = (__bf16)v;
      }
  }
}

// ---- prep: W[l][K0][128] fp32 -> Wt[l][128][Kp] bf16 (transposed, zero-pad K)
__global__ void prep_w(const float* __restrict__ W, __bf16* __restrict__ Wt,
                       int K0, int Kp) {
  int idx = blockIdx.x * 256 + threadIdx.x;
  int total = NL * HD * Kp;
  if (idx >= total) return;
  int l = idx / (HD * Kp);
  int rem = idx - l * HD * Kp;
  int n = rem / Kp;
  int k = rem - n * Kp;
  float v = (k < K0) ? W[((size_t)l * K0 + k) * HD + n] : 0.f;
  Wt[idx] = (__bf16)v;
}

// ---- h0 = x @ W_in + b_in
__global__ void h0_kernel(const float* __restrict__ x, const float* __restrict__ W,
                          const float* __restrict__ b, float* __restrict__ H32,
                          __bf16* __restrict__ HB) {
  int idx = blockIdx.x * 256 + threadIdx.x;
  if (idx >= NN * HD) return;
  int node = idx >> 7, j = idx & 127;
  const float* xr = x + node * 16;
  float s = b[j];
#pragma unroll
  for (int k = 0; k < 16; ++k) s += xr[k] * W[k * HD + j];
  H32[idx] = s;
  HB[idx] = (__bf16)s;
}

// ---- static edge attr: [rel_pos(3), dist] bf16
__global__ void ea_kernel(const float* __restrict__ pos, const int* __restrict__ ei,
                          __bf16* __restrict__ EA4) {
  int e = blockIdx.x * 256 + threadIdx.x;
  if (e >= NE) return;
  int r = ei[e], c = ei[NE + e];
  float dx = pos[c * 3 + 0] - pos[r * 3 + 0];
  float dy = pos[c * 3 + 1] - pos[r * 3 + 1];
  float dz = pos[c * 3 + 2] - pos[r * 3 + 2];
  float d = sqrtf(dx * dx + dy * dy + dz * dz);
  EA4[(size_t)e * 4 + 0] = (__bf16)dx;
  EA4[(size_t)e * 4 + 1] = (__bf16)dy;
  EA4[(size_t)e * 4 + 2] = (__bf16)dz;
  EA4[(size_t)e * 4 + 3] = (__bf16)d;
}

// ---- CSR build (counting sort of edges by col)
__global__ void hist_kernel(const int* __restrict__ ei, int* __restrict__ cnt) {
  int e = blockIdx.x * 256 + threadIdx.x;
  if (e < NE) atomicAdd(&cnt[ei[NE + e]], 1);
}

__global__ void scan_kernel(const int* __restrict__ cnt, int* __restrict__ cur) {
  __shared__ int wsum[16];
  __shared__ int carry;
  int t = threadIdx.x;           // 1024 threads
  int lane = t & 63, wid = t >> 6;
  if (t == 0) carry = 0;
  __syncthreads();
  for (int base = 0; base < NN; base += 1024) {
    int v = (base + t < NN) ? cnt[base + t] : 0;
    int incl = v;
#pragma unroll
    for (int off = 1; off < 64; off <<= 1) {
      int u = __shfl_up(incl, off, 64);
      if (lane >= off) incl += u;
    }
    if (lane == 63) wsum[wid] = incl;
    __syncthreads();
    int woff = 0;
    for (int k = 0; k < wid; ++k) woff += wsum[k];
    int c = carry;
    if (base + t < NN) cur[base + t] = c + woff + incl - v;
    __syncthreads();
    if (t == 1023) carry = c + woff + incl;
    __syncthreads();
  }
}

__global__ void scatter_kernel(const int* __restrict__ ei, int* __restrict__ cur,
                               int* __restrict__ srt) {
  int e = blockIdx.x * 256 + threadIdx.x;
  if (e < NE) {
    int p = atomicAdd(&cur[ei[NE + e]], 1);
    srt[p] = e;
  }
}

// ---- edge MLP + segmented scatter-add. 64 sorted edges per block, 256 thr.
// A tile: [64][296] bf16 : [h[col](128) | h[row](128) | ea(7) | pad0(25+)]
__global__ __launch_bounds__(256, 2) void edge_kernel(
    const __bf16* __restrict__ HB, const __bf16* __restrict__ EA4,
    const int* __restrict__ SRT, const int* __restrict__ ei,
    const __bf16* __restrict__ We1t, const __bf16* __restrict__ We2t,
    const __bf16* __restrict__ We3t,
    const float* __restrict__ be1, const float* __restrict__ be2,
    const float* __restrict__ be3, float* __restrict__ AGG)
{
  __shared__ __bf16 R1[64 * 296];   // A; later out2 (stride 136)
  __shared__ __bf16 R2[64 * 136];   // out1; later m (stride 136)
  __shared__ int colsS[64], rowsS[64], eS[64];
  const int t = threadIdx.x;
  const int base = blockIdx.x * 64;

  if (t < 64) {
    int e = SRT[base + t];
    eS[t] = e;
    rowsS[t] = ei[e];
    colsS[t] = ei[NE + e];
  }
  __syncthreads();
  {
    const int i0 = t >> 4, s = t & 15;   // 16B chunk s of edge-row i
#pragma unroll
    for (int g = 0; g < 4; ++g) {
      const int i = g * 16 + i0;
      *reinterpret_cast<uint4*>(&R1[i * 296 + s * 8]) =
          *(reinterpret_cast<const uint4*>(HB + (size_t)colsS[i] * HD) + s);
      *reinterpret_cast<uint4*>(&R1[i * 296 + 128 + s * 8]) =
          *(reinterpret_cast<const uint4*>(HB + (size_t)rowsS[i] * HD) + s);
    }
  }
  __syncthreads();
  if (t < 64) {
    const __bf16* ea = EA4 + (size_t)eS[t] * 4;
    __bf16* dst = &R1[t * 296 + 256];
    dst[0] = ea[0]; dst[1] = ea[1]; dst[2] = ea[2]; dst[3] = ea[3];
#pragma unroll
    for (int k = 0; k < 3; ++k) {    // rel_mom = h[col][3:6] - h[row][3:6]
      float rm = (float)R1[t * 296 + 3 + k] - (float)R1[t * 296 + 128 + 3 + k];
      dst[4 + k] = (__bf16)rm;
    }
#pragma unroll
    for (int k = 7; k < 32; ++k) dst[k] = (__bf16)0.0f;
  }
  __syncthreads();

  const int w = t >> 6, lane = t & 63;
  const int m_off = (w >> 1) * 32, n_off = (w & 1) * 64;
  f32x4 acc[2][4];

  zero_acc(acc);
  run_gemm<2, 4, 288>(R1, 296, We1t, m_off, n_off, lane, acc);
  store_tile<2, 4, true>(R2, 136, be1, m_off, n_off, lane, acc);
  __syncthreads();
  zero_acc(acc);
  run_gemm<2, 4, 128>(R2, 136, We2t, m_off, n_off, lane, acc);
  store_tile<2, 4, true>(R1, 136, be2, m_off, n_off, lane, acc);
  __syncthreads();
  zero_acc(acc);
  run_gemm<2, 4, 128>(R1, 136, We3t, m_off, n_off, lane, acc);
  store_tile<2, 4, false>(R2, 136, be3, m_off, n_off, lane, acc);
  __syncthreads();

  // segmented reduce over sorted cols, one atomic row-add per run
  if (t < HD) {
    float s = 0.f;
    for (int i = 0; i < 64; ++i) {
      s += (float)R2[i * 136 + t];
      const int c = colsS[i];
      if (i == 63 || colsS[i + 1] != c) {
        atomicAdd(&AGG[(size_t)c * HD + t], s);
        s = 0.f;
      }
    }
  }
}

// ---- node MLP + residual + LayerNorm. 64 nodes per block, 256 thr.
__global__ __launch_bounds__(256, 2) void node_kernel(
    const __bf16* __restrict__ HBin, const float* __restrict__ AGG,
    const __bf16* __restrict__ Wn1t, const __bf16* __restrict__ Wn2t,
    const __bf16* __restrict__ Wn3t,
    const float* __restrict__ bn1, const float* __restrict__ bn2,
    const float* __restrict__ bn3,
    const float* __restrict__ lng, const float* __restrict__ lnb,
    float* __restrict__ H32, __bf16* __restrict__ HBout,
    float* __restrict__ dout)
{
  __shared__ float R1f[64 * 133];        // A bf16 (stride 264) / out2 bf16 / h+u fp32
  __shared__ __bf16 R2[64 * 136];        // out1 / u
  __shared__ float ps[64][2], psq[64][2];
  __shared__ float mean_s[64], rstd_s[64];
  __bf16* R1 = reinterpret_cast<__bf16*>(R1f);
  const int t = threadIdx.x;
  const int base = blockIdx.x * 64;

  {
    const int i0 = t >> 4, s = t & 15;
#pragma unroll
    for (int g = 0; g < 4; ++g) {
      const int i = g * 16 + i0;
      const int node = base + i;
      uint4 v = make_uint4(0, 0, 0, 0);
      if (node < NN) v = *(reinterpret_cast<const uint4*>(HBin + (size_t)node * HD) + s);
      *reinterpret_cast<uint4*>(&R1[i * 264 + s * 8]) = v;
    }
  }
  for (int idx = t; idx < 64 * 32; idx += 256) {
    const int i = idx >> 5, c4 = idx & 31;
    const int node = base + i;
    float4 v = make_float4(0.f, 0.f, 0.f, 0.f);
    if (node < NN) v = *reinterpret_cast<const float4*>(AGG + (size_t)node * HD + c4 * 4);
    __bf16* d = &R1[i * 264 + HD + c4 * 4];
    d[0] = (__bf16)v.x; d[1] = (__bf16)v.y; d[2] = (__bf16)v.z; d[3] = (__bf16)v.w;
  }
  __syncthreads();

  const int w = t >> 6, lane = t & 63;
  const int m_off = (w >> 1) * 32, n_off = (w & 1) * 64;
  f32x4 acc[2][4];

  zero_acc(acc);
  run_gemm<2, 4, 256>(R1, 264, Wn1t, m_off, n_off, lane, acc);
  store_tile<2, 4, true>(R2, 136, bn1, m_off, n_off, lane, acc);
  __syncthreads();
  zero_acc(acc);
  run_gemm<2, 4, 128>(R2, 136, Wn2t, m_off, n_off, lane, acc);
  store_tile<2, 4, true>(R1, 136, bn2, m_off, n_off, lane, acc);
  __syncthreads();
  zero_acc(acc);
  run_gemm<2, 4, 128>(R1, 136, Wn3t, m_off, n_off, lane, acc);
  store_tile<2, 4, false>(R2, 136, bn3, m_off, n_off, lane, acc);
  __syncthreads();

  // s = h + u  -> R1f (stride 133: conflict-free for per-row scans)
  for (int idx = t; idx < 64 * HD; idx += 256) {
    const int r = idx >> 7, j = idx & 127;
    const int node = base + r;
    float hv = (node < NN) ? H32[(size_t)node * HD + j] : 0.f;
    R1f[r * 133 + j] = hv + (float)R2[r * 136 + j];
  }
  __syncthreads();
  if (t < 128) {
    const int r = t >> 1, hh = t & 1;
    float s = 0.f, sq = 0.f;
    for (int j = hh * 64; j < hh * 64 + 64; ++j) {
      float v = R1f[r * 133 + j];
      s += v; sq += v * v;
    }
    ps[r][hh] = s; psq[r][hh] = sq;
  }
  __syncthreads();
  if (t < 64) {
    float s = ps[t][0] + ps[t][1];
    float sq = psq[t][0] + psq[t][1];
    float mean = s * (1.f / HD);
    float var = sq * (1.f / HD) - mean * mean;
    mean_s[t] = mean;
    rstd_s[t] = rsqrtf(var + 1e-5f);
  }
  __syncthreads();
  for (int idx = t; idx < 64 * HD; idx += 256) {
    const int r = idx >> 7, j = idx & 127;
    const int node = base + r;
    if (node < NN) {
      float v = (R1f[r * 133 + j] - mean_s[r]) * rstd_s[r] * lng[j] + lnb[j];
      H32[(size_t)node * HD + j] = v;
      HBout[(size_t)node * HD + j] = (__bf16)v;
      if (dout) dout[(size_t)node * HD + j] = v;
    }
  }
}

extern "C" void kernel_launch(void* const* d_in, const int* in_sizes, int n_in,
                              void* d_out, int out_size, void* d_ws, size_t ws_size,
                              hipStream_t stream)
{
  const float* x    = (const float*)d_in[0];
  const float* pos  = (const float*)d_in[1];
  const int*   ei   = (const int*)d_in[2];
  const float* W_in = (const float*)d_in[3];
  const float* b_in = (const float*)d_in[4];
  const float* We1  = (const float*)d_in[5];
  const float* be1  = (const float*)d_in[6];
  const float* We2  = (const float*)d_in[7];
  const float* be2  = (const float*)d_in[8];
  const float* We3  = (const float*)d_in[9];
  const float* be3  = (const float*)d_in[10];
  const float* Wn1  = (const float*)d_in[11];
  const float* bn1  = (const float*)d_in[12];
  const float* Wn2  = (const float*)d_in[13];
  const float* bn2  = (const float*)d_in[14];
  const float* Wn3  = (const float*)d_in[15];
  const float* bn3  = (const float*)d_in[16];
  const float* lng  = (const float*)d_in[17];
  const float* lnb  = (const float*)d_in[18];
  float* out = (float*)d_out;

  char* ws = (char*)d_ws;
  size_t off = 0;
  auto alloc = [&](size_t bytes) -> char* {
    char* p = ws + off;
    off += (bytes + 255) & ~(size_t)255;
    return p;
  };
  __bf16* We1t = (__bf16*)alloc((size_t)NL * HD * 288 * 2);
  __bf16* We2t = (__bf16*)alloc((size_t)NL * HD * 128 * 2);
  __bf16* We3t = (__bf16*)alloc((size_t)NL * HD * 128 * 2);
  __bf16* Wn1t = (__bf16*)alloc((size_t)NL * HD * 256 * 2);
  __bf16* Wn2t = (__bf16*)alloc((size_t)NL * HD * 128 * 2);
  __bf16* Wn3t = (__bf16*)alloc((size_t)NL * HD * 128 * 2);
  __bf16* EA4  = (__bf16*)alloc((size_t)NE * 4 * 2);
  float*  H32  = (float*) alloc((size_t)NN * HD * 4);
  __bf16* HB   = (__bf16*)alloc((size_t)NN * HD * 2);
  float*  AGG  = (float*) alloc((size_t)NN * HD * 4);
  int*    CNT  = (int*)   alloc((size_t)NN * 4);
  int*    CUR  = (int*)   alloc((size_t)NN * 4);
  int*    SRT  = (int*)   alloc((size_t)NE * 4);

  hipMemsetAsync(CNT, 0, (size_t)NN * 4, stream);
  prep_w<<<(NL * HD * 288 + 255) / 256, 256, 0, stream>>>(We1, We1t, 263, 288);
  prep_w<<<(NL * HD * 128 + 255) / 256, 256, 0, stream>>>(We2, We2t, 128, 128);
  prep_w<<<(NL * HD * 128 + 255) / 256, 256, 0, stream>>>(We3, We3t, 128, 128);
  prep_w<<<(NL * HD * 256 + 255) / 256, 256, 0, stream>>>(Wn1, Wn1t, 256, 256);
  prep_w<<<(NL * HD * 128 + 255) / 256, 256, 0, stream>>>(Wn2, Wn2t, 128, 128);
  prep_w<<<(NL * HD * 128 + 255) / 256, 256, 0, stream>>>(Wn3, Wn3t, 128, 128);
  ea_kernel<<<(NE + 255) / 256, 256, 0, stream>>>(pos, ei, EA4);
  h0_kernel<<<(NN * HD + 255) / 256, 256, 0, stream>>>(x, W_in, b_in, H32, HB);
  hist_kernel<<<(NE + 255) / 256, 256, 0, stream>>>(ei, CNT);
  scan_kernel<<<1, 1024, 0, stream>>>(CNT, CUR);
  scatter_kernel<<<(NE + 255) / 256, 256, 0, stream>>>(ei, CUR, SRT);

  for (int l = 0; l < NL; ++l) {
    hipMemsetAsync(AGG, 0, (size_t)NN * HD * 4, stream);
    edge_kernel<<<NE / 64, 256, 0, stream>>>(HB, EA4, SRT, ei,
        We1t + (size_t)l * HD * 288, We2t + (size_t)l * HD * 128,
        We3t + (size_t)l * HD * 128,
        be1 + l * HD, be2 + l * HD, be3 + l * HD, AGG);
    node_kernel<<<(NN + 63) / 64, 256, 0, stream>>>(HB, AGG,
        Wn1t + (size_t)l * HD * 256, Wn2t + (size_t)l * HD * 128,
        Wn3t + (size_t)l * HD * 128,
        bn1 + l * HD, bn2 + l * HD, bn3 + l * HD,
        lng + l * HD, lnb + l * HD,
        H32, HB, (l == NL - 1) ? out : nullptr);
  }
}

// Round 2
// 1832.934 us; speedup vs baseline: 1.1361x; 1.1361x over previous
//
#include <hip/hip_runtime.h>
#include <stdint.h>

#define NN 50000   // nodes
#define NE 800000  // edges
#define HD 128     // hidden
#define NL 4       // layers

typedef __bf16 bf16x8 __attribute__((ext_vector_type(8)));
typedef float  f32x4  __attribute__((ext_vector_type(4)));

__device__ __forceinline__ f32x4 mfma16(bf16x8 a, bf16x8 b, f32x4 c) {
  return __builtin_amdgcn_mfma_f32_16x16x32_bf16(a, b, c, 0, 0, 0);
}

template<int MT, int NT>
__device__ __forceinline__ void zero_acc(f32x4 (&acc)[MT][NT]) {
#pragma unroll
  for (int i = 0; i < MT; ++i)
#pragma unroll
    for (int j = 0; j < NT; ++j) acc[i][j] = f32x4{0.f, 0.f, 0.f, 0.f};
}

// C[m][n] += A[m][k] * B[k][n], A in LDS (row-major, stride sa), B given
// TRANSPOSED in global (Bt[n][k], row stride K). Wave computes MT*16 x NT*16.
template<int MT, int NT, int K>
__device__ __forceinline__ void run_gemm(const __bf16* A, int sa,
    const __bf16* __restrict__ Bt, int m_off, int n_off, int lane,
    f32x4 (&acc)[MT][NT])
{
  const int arow = lane & 15;
  const int quad = lane >> 4;
#pragma unroll
  for (int ks = 0; ks < K / 32; ++ks) {
    const int k = ks * 32 + quad * 8;
    bf16x8 a[MT], b[NT];
#pragma unroll
    for (int mt = 0; mt < MT; ++mt)
      a[mt] = *reinterpret_cast<const bf16x8*>(A + (m_off + mt * 16 + arow) * sa + k);
#pragma unroll
    for (int nt = 0; nt < NT; ++nt)
      b[nt] = *reinterpret_cast<const bf16x8*>(Bt + (size_t)(n_off + nt * 16 + arow) * K + k);
#pragma unroll
    for (int mt = 0; mt < MT; ++mt)
#pragma unroll
      for (int nt = 0; nt < NT; ++nt)
        acc[mt][nt] = mfma16(a[mt], b[nt], acc[mt][nt]);
  }
}

// C/D layout (m89-verified): col = lane&15, row = (lane>>4)*4 + reg
template<int MT, int NT, bool RELU>
__device__ __forceinline__ void store_tile(__bf16* O, int so,
    const float* __restrict__ bias, int m_off, int n_off, int lane,
    f32x4 (&acc)[MT][NT])
{
  const int quad = lane >> 4;
  const int cl = lane & 15;
#pragma unroll
  for (int nt = 0; nt < NT; ++nt) {
    const int col = n_off + nt * 16 + cl;
    const float bv = bias[col];
#pragma unroll
    for (int mt = 0; mt < MT; ++mt)
#pragma unroll
      for (int r = 0; r < 4; ++r) {
        const int row = m_off + mt * 16 + quad * 4 + r;
        float v = acc[mt][nt][r] + bv;
        if (RELU) v = fmaxf(v, 0.f);
        O[row * so + col] = (__bf16)v;
      }
  }
}

// ---- prep: W[l][K0][128] fp32 -> Wt[l][128][Kp] bf16 (transposed, zero-pad K)
__global__ void prep_w(const float* __restrict__ W, __bf16* __restrict__ Wt,
                       int K0, int Kp) {
  int idx = blockIdx.x * 256 + threadIdx.x;
  int total = NL * HD * Kp;
  if (idx >= total) return;
  int l = idx / (HD * Kp);
  int rem = idx - l * HD * Kp;
  int n = rem / Kp;
  int k = rem - n * Kp;
  float v = (k < K0) ? W[((size_t)l * K0 + k) * HD + n] : 0.f;
  Wt[idx] = (__bf16)v;
}

// ---- h0 = x @ W_in + b_in
__global__ void h0_kernel(const float* __restrict__ x, const float* __restrict__ W,
                          const float* __restrict__ b, float* __restrict__ H32,
                          __bf16* __restrict__ HB) {
  int idx = blockIdx.x * 256 + threadIdx.x;
  if (idx >= NN * HD) return;
  int node = idx >> 7, j = idx & 127;
  const float* xr = x + node * 16;
  float s = b[j];
#pragma unroll
  for (int k = 0; k < 16; ++k) s += xr[k] * W[k * HD + j];
  H32[idx] = s;
  HB[idx] = (__bf16)s;
}

// ---- static edge attr: [rel_pos(3), dist] bf16
__global__ void ea_kernel(const float* __restrict__ pos, const int* __restrict__ ei,
                          __bf16* __restrict__ EA4) {
  int e = blockIdx.x * 256 + threadIdx.x;
  if (e >= NE) return;
  int r = ei[e], c = ei[NE + e];
  float dx = pos[c * 3 + 0] - pos[r * 3 + 0];
  float dy = pos[c * 3 + 1] - pos[r * 3 + 1];
  float dz = pos[c * 3 + 2] - pos[r * 3 + 2];
  float d = sqrtf(dx * dx + dy * dy + dz * dz);
  EA4[(size_t)e * 4 + 0] = (__bf16)dx;
  EA4[(size_t)e * 4 + 1] = (__bf16)dy;
  EA4[(size_t)e * 4 + 2] = (__bf16)dz;
  EA4[(size_t)e * 4 + 3] = (__bf16)d;
}

// ---- CSR build (counting sort of edges by col)
__global__ void hist_kernel(const int* __restrict__ ei, int* __restrict__ cnt) {
  int e = blockIdx.x * 256 + threadIdx.x;
  if (e < NE) atomicAdd(&cnt[ei[NE + e]], 1);
}

__global__ void scan_kernel(const int* __restrict__ cnt, int* __restrict__ cur) {
  __shared__ int wsum[16];
  __shared__ int carry;
  int t = threadIdx.x;           // 1024 threads
  int lane = t & 63, wid = t >> 6;
  if (t == 0) carry = 0;
  __syncthreads();
  for (int base = 0; base < NN; base += 1024) {
    int v = (base + t < NN) ? cnt[base + t] : 0;
    int incl = v;
#pragma unroll
    for (int off = 1; off < 64; off <<= 1) {
      int u = __shfl_up(incl, off, 64);
      if (lane >= off) incl += u;
    }
    if (lane == 63) wsum[wid] = incl;
    __syncthreads();
    int woff = 0;
    for (int k = 0; k < wid; ++k) woff += wsum[k];
    int c = carry;
    if (base + t < NN) cur[base + t] = c + woff + incl - v;
    __syncthreads();
    if (t == 1023) carry = c + woff + incl;
    __syncthreads();
  }
}

__global__ void scatter_kernel(const int* __restrict__ ei, int* __restrict__ cur,
                               int* __restrict__ srt) {
  int e = blockIdx.x * 256 + threadIdx.x;
  if (e < NE) {
    int p = atomicAdd(&cur[ei[NE + e]], 1);
    srt[p] = e;
  }
}

// ---- edge MLP + segmented scatter-add. 64 sorted edges per block, 256 thr.
// Single LDS buffer R1 (64x296 bf16 = 37,888 B), time-multiplexed:
//   phase A  : A tile [h[col]|h[row]|ea|pad] stride 296
//   out1     : bf16 offset 0,    stride 136 (17,408 B)
//   out2     : bf16 offset 8704, stride 136
//   m (out3) : bf16 offset 0,    stride 136
// -> ~38.7 KB total => 4 blocks/CU (was 56.3 KB => 2 blocks/CU)
__global__ __launch_bounds__(256, 4) void edge_kernel(
    const __bf16* __restrict__ HB, const __bf16* __restrict__ EA4,
    const int* __restrict__ SRT, const int* __restrict__ ei,
    const __bf16* __restrict__ We1t, const __bf16* __restrict__ We2t,
    const __bf16* __restrict__ We3t,
    const float* __restrict__ be1, const float* __restrict__ be2,
    const float* __restrict__ be3, float* __restrict__ AGG)
{
  __shared__ __bf16 R1[64 * 296];
  __shared__ int colsS[64], rowsS[64], eS[64];
  const int t = threadIdx.x;
  const int base = blockIdx.x * 64;

  if (t < 64) {
    int e = SRT[base + t];
    eS[t] = e;
    rowsS[t] = ei[e];
    colsS[t] = ei[NE + e];
  }
  __syncthreads();
  {
    const int i0 = t >> 4, s = t & 15;   // 16B chunk s of edge-row i
#pragma unroll
    for (int g = 0; g < 4; ++g) {
      const int i = g * 16 + i0;
      *reinterpret_cast<uint4*>(&R1[i * 296 + s * 8]) =
          *(reinterpret_cast<const uint4*>(HB + (size_t)colsS[i] * HD) + s);
      *reinterpret_cast<uint4*>(&R1[i * 296 + 128 + s * 8]) =
          *(reinterpret_cast<const uint4*>(HB + (size_t)rowsS[i] * HD) + s);
    }
  }
  __syncthreads();
  if (t < 64) {
    const __bf16* ea = EA4 + (size_t)eS[t] * 4;
    __bf16* dst = &R1[t * 296 + 256];
    dst[0] = ea[0]; dst[1] = ea[1]; dst[2] = ea[2]; dst[3] = ea[3];
#pragma unroll
    for (int k = 0; k < 3; ++k) {    // rel_mom = h[col][3:6] - h[row][3:6]
      float rm = (float)R1[t * 296 + 3 + k] - (float)R1[t * 296 + 128 + 3 + k];
      dst[4 + k] = (__bf16)rm;
    }
#pragma unroll
    for (int k = 7; k < 32; ++k) dst[k] = (__bf16)0.0f;
  }
  __syncthreads();

  const int w = t >> 6, lane = t & 63;
  const int m_off = (w >> 1) * 32, n_off = (w & 1) * 64;
  f32x4 acc[2][4];
  __bf16* reg0 = R1;          // stride 136 staging, bytes [0, 17408)
  __bf16* reg1 = R1 + 8704;   // stride 136 staging, bytes [17408, 34816)

  zero_acc(acc);
  run_gemm<2, 4, 288>(R1, 296, We1t, m_off, n_off, lane, acc);
  __syncthreads();                       // all waves done reading A before overwrite
  store_tile<2, 4, true>(reg0, 136, be1, m_off, n_off, lane, acc);
  __syncthreads();
  zero_acc(acc);
  run_gemm<2, 4, 128>(reg0, 136, We2t, m_off, n_off, lane, acc);
  store_tile<2, 4, true>(reg1, 136, be2, m_off, n_off, lane, acc);  // disjoint from reg0
  __syncthreads();
  zero_acc(acc);
  run_gemm<2, 4, 128>(reg1, 136, We3t, m_off, n_off, lane, acc);
  store_tile<2, 4, false>(reg0, 136, be3, m_off, n_off, lane, acc); // reg0 dead since gemm2
  __syncthreads();

  // segmented reduce over sorted cols; 256 threads: col t&127, row-half t>>7.
  // Runs crossing the half boundary emit two partial atomics (correct).
  {
    const int j = t & 127, hh = t >> 7;
    const int i0 = hh * 32, i1 = i0 + 32;
    float s = 0.f;
    for (int i = i0; i < i1; ++i) {
      s += (float)reg0[i * 136 + j];
      const int c = colsS[i];
      if (i == i1 - 1 || colsS[i + 1] != c) {
        atomicAdd(&AGG[(size_t)c * HD + j], s);
        s = 0.f;
      }
    }
  }
}

// ---- node MLP + residual + LayerNorm. 64 nodes per block, 256 thr.
// Single union buffer SB (64*136 f32 = 34,816 B), time-multiplexed:
//   A tile : bf16 view, stride 264 (33,792 B)
//   out1   : bf16 offset 0,    stride 136
//   out2   : bf16 offset 8704, stride 136
//   s=h+u  : f32, stride 136 (34,816 B)  [GEMM3 epilogue fuses H32 read]
__global__ __launch_bounds__(256, 4) void node_kernel(
    const __bf16* __restrict__ HBin, const float* __restrict__ AGG,
    const __bf16* __restrict__ Wn1t, const __bf16* __restrict__ Wn2t,
    const __bf16* __restrict__ Wn3t,
    const float* __restrict__ bn1, const float* __restrict__ bn2,
    const float* __restrict__ bn3,
    const float* __restrict__ lng, const float* __restrict__ lnb,
    float* __restrict__ H32, __bf16* __restrict__ HBout,
    float* __restrict__ dout)
{
  __shared__ float SB[64 * 136];
  __shared__ float ps[64][2], psq[64][2];
  __shared__ float mean_s[64], rstd_s[64];
  __bf16* B16 = reinterpret_cast<__bf16*>(SB);
  const int t = threadIdx.x;
  const int base = blockIdx.x * 64;

  {
    const int i0 = t >> 4, s = t & 15;
#pragma unroll
    for (int g = 0; g < 4; ++g) {
      const int i = g * 16 + i0;
      const int node = base + i;
      uint4 v = make_uint4(0, 0, 0, 0);
      if (node < NN) v = *(reinterpret_cast<const uint4*>(HBin + (size_t)node * HD) + s);
      *reinterpret_cast<uint4*>(&B16[i * 264 + s * 8]) = v;
    }
  }
  for (int idx = t; idx < 64 * 32; idx += 256) {
    const int i = idx >> 5, c4 = idx & 31;
    const int node = base + i;
    float4 v = make_float4(0.f, 0.f, 0.f, 0.f);
    if (node < NN) v = *reinterpret_cast<const float4*>(AGG + (size_t)node * HD + c4 * 4);
    __bf16* d = &B16[i * 264 + HD + c4 * 4];
    d[0] = (__bf16)v.x; d[1] = (__bf16)v.y; d[2] = (__bf16)v.z; d[3] = (__bf16)v.w;
  }
  __syncthreads();

  const int w = t >> 6, lane = t & 63;
  const int m_off = (w >> 1) * 32, n_off = (w & 1) * 64;
  f32x4 acc[2][4];
  __bf16* reg0 = B16;
  __bf16* reg1 = B16 + 8704;

  zero_acc(acc);
  run_gemm<2, 4, 256>(B16, 264, Wn1t, m_off, n_off, lane, acc);
  __syncthreads();                       // A dead after this
  store_tile<2, 4, true>(reg0, 136, bn1, m_off, n_off, lane, acc);
  __syncthreads();
  zero_acc(acc);
  run_gemm<2, 4, 128>(reg0, 136, Wn2t, m_off, n_off, lane, acc);
  store_tile<2, 4, true>(reg1, 136, bn2, m_off, n_off, lane, acc);
  __syncthreads();
  zero_acc(acc);
  run_gemm<2, 4, 128>(reg1, 136, Wn3t, m_off, n_off, lane, acc);
  __syncthreads();                       // all reads of reg1 done before f32 overwrite

  // epilogue: s = h + u (+bias), fp32 into SB stride 136, fused H32 read
  {
    const int quad = lane >> 4, cl = lane & 15;
#pragma unroll
    for (int nt = 0; nt < 4; ++nt) {
      const int col = n_off + nt * 16 + cl;
      const float bv = bn3[col];
#pragma unroll
      for (int mt = 0; mt < 2; ++mt)
#pragma unroll
        for (int r = 0; r < 4; ++r) {
          const int row = m_off + mt * 16 + quad * 4 + r;
          const int node = base + row;
          float hv = (node < NN) ? H32[(size_t)node * HD + col] : 0.f;
          SB[row * 136 + col] = hv + acc[mt][nt][r] + bv;
        }
    }
  }
  __syncthreads();
  if (t < 128) {
    const int r = t >> 1, hh = t & 1;
    float s = 0.f, sq = 0.f;
    for (int j = hh * 64; j < hh * 64 + 64; ++j) {
      float v = SB[r * 136 + j];
      s += v; sq += v * v;
    }
    ps[r][hh] = s; psq[r][hh] = sq;
  }
  __syncthreads();
  if (t < 64) {
    float s = ps[t][0] + ps[t][1];
    float sq = psq[t][0] + psq[t][1];
    float mean = s * (1.f / HD);
    float var = sq * (1.f / HD) - mean * mean;
    mean_s[t] = mean;
    rstd_s[t] = rsqrtf(var + 1e-5f);
  }
  __syncthreads();
  for (int idx = t; idx < 64 * HD; idx += 256) {
    const int r = idx >> 7, j = idx & 127;
    const int node = base + r;
    if (node < NN) {
      float v = (SB[r * 136 + j] - mean_s[r]) * rstd_s[r] * lng[j] + lnb[j];
      H32[(size_t)node * HD + j] = v;
      HBout[(size_t)node * HD + j] = (__bf16)v;
      if (dout) dout[(size_t)node * HD + j] = v;
    }
  }
}

extern "C" void kernel_launch(void* const* d_in, const int* in_sizes, int n_in,
                              void* d_out, int out_size, void* d_ws, size_t ws_size,
                              hipStream_t stream)
{
  const float* x    = (const float*)d_in[0];
  const float* pos  = (const float*)d_in[1];
  const int*   ei   = (const int*)d_in[2];
  const float* W_in = (const float*)d_in[3];
  const float* b_in = (const float*)d_in[4];
  const float* We1  = (const float*)d_in[5];
  const float* be1  = (const float*)d_in[6];
  const float* We2  = (const float*)d_in[7];
  const float* be2  = (const float*)d_in[8];
  const float* We3  = (const float*)d_in[9];
  const float* be3  = (const float*)d_in[10];
  const float* Wn1  = (const float*)d_in[11];
  const float* bn1  = (const float*)d_in[12];
  const float* Wn2  = (const float*)d_in[13];
  const float* bn2  = (const float*)d_in[14];
  const float* Wn3  = (const float*)d_in[15];
  const float* bn3  = (const float*)d_in[16];
  const float* lng  = (const float*)d_in[17];
  const float* lnb  = (const float*)d_in[18];
  float* out = (float*)d_out;

  char* ws = (char*)d_ws;
  size_t off = 0;
  auto alloc = [&](size_t bytes) -> char* {
    char* p = ws + off;
    off += (bytes + 255) & ~(size_t)255;
    return p;
  };
  __bf16* We1t = (__bf16*)alloc((size_t)NL * HD * 288 * 2);
  __bf16* We2t = (__bf16*)alloc((size_t)NL * HD * 128 * 2);
  __bf16* We3t = (__bf16*)alloc((size_t)NL * HD * 128 * 2);
  __bf16* Wn1t = (__bf16*)alloc((size_t)NL * HD * 256 * 2);
  __bf16* Wn2t = (__bf16*)alloc((size_t)NL * HD * 128 * 2);
  __bf16* Wn3t = (__bf16*)alloc((size_t)NL * HD * 128 * 2);
  __bf16* EA4  = (__bf16*)alloc((size_t)NE * 4 * 2);
  float*  H32  = (float*) alloc((size_t)NN * HD * 4);
  __bf16* HB   = (__bf16*)alloc((size_t)NN * HD * 2);
  float*  AGG  = (float*) alloc((size_t)NN * HD * 4);
  int*    CNT  = (int*)   alloc((size_t)NN * 4);
  int*    CUR  = (int*)   alloc((size_t)NN * 4);
  int*    SRT  = (int*)   alloc((size_t)NE * 4);

  hipMemsetAsync(CNT, 0, (size_t)NN * 4, stream);
  prep_w<<<(NL * HD * 288 + 255) / 256, 256, 0, stream>>>(We1, We1t, 263, 288);
  prep_w<<<(NL * HD * 128 + 255) / 256, 256, 0, stream>>>(We2, We2t, 128, 128);
  prep_w<<<(NL * HD * 128 + 255) / 256, 256, 0, stream>>>(We3, We3t, 128, 128);
  prep_w<<<(NL * HD * 256 + 255) / 256, 256, 0, stream>>>(Wn1, Wn1t, 256, 256);
  prep_w<<<(NL * HD * 128 + 255) / 256, 256, 0, stream>>>(Wn2, Wn2t, 128, 128);
  prep_w<<<(NL * HD * 128 + 255) / 256, 256, 0, stream>>>(Wn3, Wn3t, 128, 128);
  ea_kernel<<<(NE + 255) / 256, 256, 0, stream>>>(pos, ei, EA4);
  h0_kernel<<<(NN * HD + 255) / 256, 256, 0, stream>>>(x, W_in, b_in, H32, HB);
  hist_kernel<<<(NE + 255) / 256, 256, 0, stream>>>(ei, CNT);
  scan_kernel<<<1, 1024, 0, stream>>>(CNT, CUR);
  scatter_kernel<<<(NE + 255) / 256, 256, 0, stream>>>(ei, CUR, SRT);

  for (int l = 0; l < NL; ++l) {
    hipMemsetAsync(AGG, 0, (size_t)NN * HD * 4, stream);
    edge_kernel<<<NE / 64, 256, 0, stream>>>(HB, EA4, SRT, ei,
        We1t + (size_t)l * HD * 288, We2t + (size_t)l * HD * 128,
        We3t + (size_t)l * HD * 128,
        be1 + l * HD, be2 + l * HD, be3 + l * HD, AGG);
    node_kernel<<<(NN + 63) / 64, 256, 0, stream>>>(HB, AGG,
        Wn1t + (size_t)l * HD * 256, Wn2t + (size_t)l * HD * 128,
        Wn3t + (size_t)l * HD * 128,
        bn1 + l * HD, bn2 + l * HD, bn3 + l * HD,
        lng + l * HD, lnb + l * HD,
        H32, HB, (l == NL - 1) ? out : nullptr);
  }
}

// Round 3
// 1657.039 us; speedup vs baseline: 1.2567x; 1.1062x over previous
//
#include <hip/hip_runtime.h>
#include <stdint.h>

#define NN 50000   // nodes
#define NE 800000  // edges
#define HD 128     // hidden
#define NL 4       // layers
#define EM 128     // edges (or nodes) per block

typedef __bf16 bf16x8 __attribute__((ext_vector_type(8)));
typedef float  f32x4  __attribute__((ext_vector_type(4)));

__device__ __forceinline__ f32x4 mfma16(bf16x8 a, bf16x8 b, f32x4 c) {
  return __builtin_amdgcn_mfma_f32_16x16x32_bf16(a, b, c, 0, 0, 0);
}

template<int MT, int NT>
__device__ __forceinline__ void zero_acc(f32x4 (&acc)[MT][NT]) {
#pragma unroll
  for (int i = 0; i < MT; ++i)
#pragma unroll
    for (int j = 0; j < NT; ++j) acc[i][j] = f32x4{0.f, 0.f, 0.f, 0.f};
}

// One K-chunk of C += A*B. A in LDS (row-major, stride sa elements), B
// transposed in global (Bt[n][Krow]). KS = # of 32-wide k-steps.
// KEY: all B fragments for the chunk are loaded into registers FIRST
// (independent loads, one vmcnt drain), then the MFMA loop runs on LDS A.
template<int MT, int NT, int KS>
__device__ __forceinline__ void gemm_chunk(const __bf16* A, int sa,
    const __bf16* __restrict__ Bt, int Krow, int k0,
    int m_off, int n_off, int lane, f32x4 (&acc)[MT][NT])
{
  const int arow = lane & 15;
  const int quad = lane >> 4;
  bf16x8 b[KS][NT];
#pragma unroll
  for (int ks = 0; ks < KS; ++ks)
#pragma unroll
    for (int nt = 0; nt < NT; ++nt)
      b[ks][nt] = *reinterpret_cast<const bf16x8*>(
          Bt + (size_t)(n_off + nt * 16 + arow) * Krow + k0 + ks * 32 + quad * 8);
#pragma unroll
  for (int ks = 0; ks < KS; ++ks) {
    const int k = k0 + ks * 32 + quad * 8;
    bf16x8 a[MT];
#pragma unroll
    for (int mt = 0; mt < MT; ++mt)
      a[mt] = *reinterpret_cast<const bf16x8*>(A + (m_off + mt * 16 + arow) * sa + k);
#pragma unroll
    for (int mt = 0; mt < MT; ++mt)
#pragma unroll
      for (int nt = 0; nt < NT; ++nt)
        acc[mt][nt] = mfma16(a[mt], b[ks][nt], acc[mt][nt]);
  }
}

// C/D layout (m89-verified): col = lane&15, row = (lane>>4)*4 + reg
template<int MT, int NT, bool RELU>
__device__ __forceinline__ void store_tile(__bf16* O, int so,
    const float* __restrict__ bias, int m_off, int n_off, int lane,
    f32x4 (&acc)[MT][NT])
{
  const int quad = lane >> 4;
  const int cl = lane & 15;
#pragma unroll
  for (int nt = 0; nt < NT; ++nt) {
    const int col = n_off + nt * 16 + cl;
    const float bv = bias[col];
#pragma unroll
    for (int mt = 0; mt < MT; ++mt)
#pragma unroll
      for (int r = 0; r < 4; ++r) {
        const int row = m_off + mt * 16 + quad * 4 + r;
        float v = acc[mt][nt][r] + bv;
        if (RELU) v = fmaxf(v, 0.f);
        O[row * so + col] = (__bf16)v;
      }
  }
}

// ---- prep: W[l][K0][128] fp32 -> Wt[l][128][Kp] bf16 (transposed, zero-pad K)
__global__ void prep_w(const float* __restrict__ W, __bf16* __restrict__ Wt,
                       int K0, int Kp) {
  int idx = blockIdx.x * 256 + threadIdx.x;
  int total = NL * HD * Kp;
  if (idx >= total) return;
  int l = idx / (HD * Kp);
  int rem = idx - l * HD * Kp;
  int n = rem / Kp;
  int k = rem - n * Kp;
  float v = (k < K0) ? W[((size_t)l * K0 + k) * HD + n] : 0.f;
  Wt[idx] = (__bf16)v;
}

// ---- h0 = x @ W_in + b_in
__global__ void h0_kernel(const float* __restrict__ x, const float* __restrict__ W,
                          const float* __restrict__ b, float* __restrict__ H32,
                          __bf16* __restrict__ HB) {
  int idx = blockIdx.x * 256 + threadIdx.x;
  if (idx >= NN * HD) return;
  int node = idx >> 7, j = idx & 127;
  const float* xr = x + node * 16;
  float s = b[j];
#pragma unroll
  for (int k = 0; k < 16; ++k) s += xr[k] * W[k * HD + j];
  H32[idx] = s;
  HB[idx] = (__bf16)s;
}

// ---- static edge attr: [rel_pos(3), dist] bf16
__global__ void ea_kernel(const float* __restrict__ pos, const int* __restrict__ ei,
                          __bf16* __restrict__ EA4) {
  int e = blockIdx.x * 256 + threadIdx.x;
  if (e >= NE) return;
  int r = ei[e], c = ei[NE + e];
  float dx = pos[c * 3 + 0] - pos[r * 3 + 0];
  float dy = pos[c * 3 + 1] - pos[r * 3 + 1];
  float dz = pos[c * 3 + 2] - pos[r * 3 + 2];
  float d = sqrtf(dx * dx + dy * dy + dz * dz);
  EA4[(size_t)e * 4 + 0] = (__bf16)dx;
  EA4[(size_t)e * 4 + 1] = (__bf16)dy;
  EA4[(size_t)e * 4 + 2] = (__bf16)dz;
  EA4[(size_t)e * 4 + 3] = (__bf16)d;
}

// ---- CSR build (counting sort of edges by col)
__global__ void hist_kernel(const int* __restrict__ ei, int* __restrict__ cnt) {
  int e = blockIdx.x * 256 + threadIdx.x;
  if (e < NE) atomicAdd(&cnt[ei[NE + e]], 1);
}

__global__ void scan_kernel(const int* __restrict__ cnt, int* __restrict__ cur) {
  __shared__ int wsum[16];
  __shared__ int carry;
  int t = threadIdx.x;           // 1024 threads
  int lane = t & 63, wid = t >> 6;
  if (t == 0) carry = 0;
  __syncthreads();
  for (int base = 0; base < NN; base += 1024) {
    int v = (base + t < NN) ? cnt[base + t] : 0;
    int incl = v;
#pragma unroll
    for (int off = 1; off < 64; off <<= 1) {
      int u = __shfl_up(incl, off, 64);
      if (lane >= off) incl += u;
    }
    if (lane == 63) wsum[wid] = incl;
    __syncthreads();
    int woff = 0;
    for (int k = 0; k < wid; ++k) woff += wsum[k];
    int c = carry;
    if (base + t < NN) cur[base + t] = c + woff + incl - v;
    __syncthreads();
    if (t == 1023) carry = c + woff + incl;
    __syncthreads();
  }
}

__global__ void scatter_kernel(const int* __restrict__ ei, int* __restrict__ cur,
                               int* __restrict__ srt) {
  int e = blockIdx.x * 256 + threadIdx.x;
  if (e < NE) {
    int p = atomicAdd(&cur[ei[NE + e]], 1);
    srt[p] = e;
  }
}

// ---- edge MLP + segmented scatter-add. 128 sorted edges/block, 256 thr.
// LDS R1 (128x296 bf16 = 75,776 B), time-multiplexed:
//   A tile : stride 296
//   out1   : bf16 offset 0,     stride 136 (34,816 B)
//   out2   : bf16 offset 17408, stride 136
//   m      : bf16 offset 0,     stride 136
// Wave tile: 64(m) x 64(n) via MT=4, NT=4. 2 blocks/CU.
__global__ __launch_bounds__(256, 2) void edge_kernel(
    const __bf16* __restrict__ HB, const __bf16* __restrict__ EA4,
    const int* __restrict__ SRT, const int* __restrict__ ei,
    const __bf16* __restrict__ We1t, const __bf16* __restrict__ We2t,
    const __bf16* __restrict__ We3t,
    const float* __restrict__ be1, const float* __restrict__ be2,
    const float* __restrict__ be3, float* __restrict__ AGG)
{
  __shared__ __bf16 R1[EM * 296];
  __shared__ int colsS[EM], rowsS[EM], eS[EM];
  const int t = threadIdx.x;
  const int base = blockIdx.x * EM;

  if (t < EM) {
    int e = SRT[base + t];
    eS[t] = e;
    rowsS[t] = ei[e];
    colsS[t] = ei[NE + e];
  }
  __syncthreads();
  {
    const int i0 = t >> 4, s = t & 15;   // 16B chunk s of edge-row i
#pragma unroll
    for (int g = 0; g < EM / 16; ++g) {
      const int i = g * 16 + i0;
      *reinterpret_cast<uint4*>(&R1[i * 296 + s * 8]) =
          *(reinterpret_cast<const uint4*>(HB + (size_t)colsS[i] * HD) + s);
      *reinterpret_cast<uint4*>(&R1[i * 296 + 128 + s * 8]) =
          *(reinterpret_cast<const uint4*>(HB + (size_t)rowsS[i] * HD) + s);
    }
  }
  __syncthreads();
  if (t < EM) {
    const __bf16* ea = EA4 + (size_t)eS[t] * 4;
    __bf16* dst = &R1[t * 296 + 256];
    dst[0] = ea[0]; dst[1] = ea[1]; dst[2] = ea[2]; dst[3] = ea[3];
#pragma unroll
    for (int k = 0; k < 3; ++k) {    // rel_mom = h[col][3:6] - h[row][3:6]
      float rm = (float)R1[t * 296 + 3 + k] - (float)R1[t * 296 + 128 + 3 + k];
      dst[4 + k] = (__bf16)rm;
    }
#pragma unroll
    for (int k = 7; k < 32; ++k) dst[k] = (__bf16)0.0f;
  }
  __syncthreads();

  const int w = t >> 6, lane = t & 63;
  const int m_off = (w >> 1) * 64, n_off = (w & 1) * 64;
  f32x4 acc[4][4];
  __bf16* reg0 = R1;               // stride 136, bytes [0, 34816)
  __bf16* reg1 = R1 + EM * 136;    // stride 136, bytes [34816, 69632)

  zero_acc(acc);
  gemm_chunk<4, 4, 3>(R1, 296, We1t, 288, 0,   m_off, n_off, lane, acc);
  gemm_chunk<4, 4, 3>(R1, 296, We1t, 288, 96,  m_off, n_off, lane, acc);
  gemm_chunk<4, 4, 3>(R1, 296, We1t, 288, 192, m_off, n_off, lane, acc);
  __syncthreads();                       // all waves done reading A
  store_tile<4, 4, true>(reg0, 136, be1, m_off, n_off, lane, acc);
  __syncthreads();
  zero_acc(acc);
  gemm_chunk<4, 4, 4>(reg0, 136, We2t, 128, 0, m_off, n_off, lane, acc);
  store_tile<4, 4, true>(reg1, 136, be2, m_off, n_off, lane, acc);  // disjoint
  __syncthreads();
  zero_acc(acc);
  gemm_chunk<4, 4, 4>(reg1, 136, We3t, 128, 0, m_off, n_off, lane, acc);
  store_tile<4, 4, false>(reg0, 136, be3, m_off, n_off, lane, acc); // reg0 dead
  __syncthreads();

  // segmented reduce over sorted cols; col t&127, row-half t>>7 (64 rows each).
  // Runs crossing the half boundary emit two partial atomics (correct).
  {
    const int j = t & 127, hh = t >> 7;
    const int i0 = hh * 64, i1 = i0 + 64;
    float s = 0.f;
    for (int i = i0; i < i1; ++i) {
      s += (float)reg0[i * 136 + j];
      const int c = colsS[i];
      if (i == i1 - 1 || colsS[i + 1] != c) {
        atomicAdd(&AGG[(size_t)c * HD + j], s);
        s = 0.f;
      }
    }
  }
}

// ---- node MLP + residual + LayerNorm. 128 nodes/block, 256 thr.
// Union buffer SB (128*136 f32 = 69,632 B):
//   A tile : bf16 view, stride 264 (67,584 B)
//   out1   : bf16 offset 0,     stride 136
//   out2   : bf16 offset 17408, stride 136
//   s=h+u  : f32, stride 136 (GEMM3 epilogue fuses H32 read)
__global__ __launch_bounds__(256, 2) void node_kernel(
    const __bf16* __restrict__ HBin, const float* __restrict__ AGG,
    const __bf16* __restrict__ Wn1t, const __bf16* __restrict__ Wn2t,
    const __bf16* __restrict__ Wn3t,
    const float* __restrict__ bn1, const float* __restrict__ bn2,
    const float* __restrict__ bn3,
    const float* __restrict__ lng, const float* __restrict__ lnb,
    float* __restrict__ H32, __bf16* __restrict__ HBout,
    float* __restrict__ dout)
{
  __shared__ float SB[EM * 136];
  __shared__ float ps[EM][2], psq[EM][2];
  __shared__ float mean_s[EM], rstd_s[EM];
  __bf16* B16 = reinterpret_cast<__bf16*>(SB);
  const int t = threadIdx.x;
  const int base = blockIdx.x * EM;

  {
    const int i0 = t >> 4, s = t & 15;
#pragma unroll
    for (int g = 0; g < EM / 16; ++g) {
      const int i = g * 16 + i0;
      const int node = base + i;
      uint4 v = make_uint4(0, 0, 0, 0);
      if (node < NN) v = *(reinterpret_cast<const uint4*>(HBin + (size_t)node * HD) + s);
      *reinterpret_cast<uint4*>(&B16[i * 264 + s * 8]) = v;
    }
  }
  for (int idx = t; idx < EM * 32; idx += 256) {
    const int i = idx >> 5, c4 = idx & 31;
    const int node = base + i;
    float4 v = make_float4(0.f, 0.f, 0.f, 0.f);
    if (node < NN) v = *reinterpret_cast<const float4*>(AGG + (size_t)node * HD + c4 * 4);
    __bf16* d = &B16[i * 264 + HD + c4 * 4];
    d[0] = (__bf16)v.x; d[1] = (__bf16)v.y; d[2] = (__bf16)v.z; d[3] = (__bf16)v.w;
  }
  __syncthreads();

  const int w = t >> 6, lane = t & 63;
  const int m_off = (w >> 1) * 64, n_off = (w & 1) * 64;
  f32x4 acc[4][4];
  __bf16* reg0 = B16;
  __bf16* reg1 = B16 + EM * 136;

  zero_acc(acc);
  gemm_chunk<4, 4, 4>(B16, 264, Wn1t, 256, 0,   m_off, n_off, lane, acc);
  gemm_chunk<4, 4, 4>(B16, 264, Wn1t, 256, 128, m_off, n_off, lane, acc);
  __syncthreads();                       // A dead after this
  store_tile<4, 4, true>(reg0, 136, bn1, m_off, n_off, lane, acc);
  __syncthreads();
  zero_acc(acc);
  gemm_chunk<4, 4, 4>(reg0, 136, Wn2t, 128, 0, m_off, n_off, lane, acc);
  store_tile<4, 4, true>(reg1, 136, bn2, m_off, n_off, lane, acc);
  __syncthreads();
  zero_acc(acc);
  gemm_chunk<4, 4, 4>(reg1, 136, Wn3t, 128, 0, m_off, n_off, lane, acc);
  __syncthreads();                       // reg1 reads done before f32 overwrite

  // epilogue: s = h + u (+bias), fp32 into SB stride 136, fused H32 read
  {
    const int quad = lane >> 4, cl = lane & 15;
#pragma unroll
    for (int nt = 0; nt < 4; ++nt) {
      const int col = n_off + nt * 16 + cl;
      const float bv = bn3[col];
#pragma unroll
      for (int mt = 0; mt < 4; ++mt)
#pragma unroll
        for (int r = 0; r < 4; ++r) {
          const int row = m_off + mt * 16 + quad * 4 + r;
          const int node = base + row;
          float hv = (node < NN) ? H32[(size_t)node * HD + col] : 0.f;
          SB[row * 136 + col] = hv + acc[mt][nt][r] + bv;
        }
    }
  }
  __syncthreads();
  {
    const int r = t >> 1, hh = t & 1;    // 256 threads = 128 rows x 2 halves
    float s = 0.f, sq = 0.f;
    for (int j = hh * 64; j < hh * 64 + 64; ++j) {
      float v = SB[r * 136 + j];
      s += v; sq += v * v;
    }
    ps[r][hh] = s; psq[r][hh] = sq;
  }
  __syncthreads();
  if (t < EM) {
    float s = ps[t][0] + ps[t][1];
    float sq = psq[t][0] + psq[t][1];
    float mean = s * (1.f / HD);
    float var = sq * (1.f / HD) - mean * mean;
    mean_s[t] = mean;
    rstd_s[t] = rsqrtf(var + 1e-5f);
  }
  __syncthreads();
  for (int idx = t; idx < EM * HD; idx += 256) {
    const int r = idx >> 7, j = idx & 127;
    const int node = base + r;
    if (node < NN) {
      float v = (SB[r * 136 + j] - mean_s[r]) * rstd_s[r] * lng[j] + lnb[j];
      H32[(size_t)node * HD + j] = v;
      HBout[(size_t)node * HD + j] = (__bf16)v;
      if (dout) dout[(size_t)node * HD + j] = v;
    }
  }
}

extern "C" void kernel_launch(void* const* d_in, const int* in_sizes, int n_in,
                              void* d_out, int out_size, void* d_ws, size_t ws_size,
                              hipStream_t stream)
{
  const float* x    = (const float*)d_in[0];
  const float* pos  = (const float*)d_in[1];
  const int*   ei   = (const int*)d_in[2];
  const float* W_in = (const float*)d_in[3];
  const float* b_in = (const float*)d_in[4];
  const float* We1  = (const float*)d_in[5];
  const float* be1  = (const float*)d_in[6];
  const float* We2  = (const float*)d_in[7];
  const float* be2  = (const float*)d_in[8];
  const float* We3  = (const float*)d_in[9];
  const float* be3  = (const float*)d_in[10];
  const float* Wn1  = (const float*)d_in[11];
  const float* bn1  = (const float*)d_in[12];
  const float* Wn2  = (const float*)d_in[13];
  const float* bn2  = (const float*)d_in[14];
  const float* Wn3  = (const float*)d_in[15];
  const float* bn3  = (const float*)d_in[16];
  const float* lng  = (const float*)d_in[17];
  const float* lnb  = (const float*)d_in[18];
  float* out = (float*)d_out;

  char* ws = (char*)d_ws;
  size_t off = 0;
  auto alloc = [&](size_t bytes) -> char* {
    char* p = ws + off;
    off += (bytes + 255) & ~(size_t)255;
    return p;
  };
  __bf16* We1t = (__bf16*)alloc((size_t)NL * HD * 288 * 2);
  __bf16* We2t = (__bf16*)alloc((size_t)NL * HD * 128 * 2);
  __bf16* We3t = (__bf16*)alloc((size_t)NL * HD * 128 * 2);
  __bf16* Wn1t = (__bf16*)alloc((size_t)NL * HD * 256 * 2);
  __bf16* Wn2t = (__bf16*)alloc((size_t)NL * HD * 128 * 2);
  __bf16* Wn3t = (__bf16*)alloc((size_t)NL * HD * 128 * 2);
  __bf16* EA4  = (__bf16*)alloc((size_t)NE * 4 * 2);
  float*  H32  = (float*) alloc((size_t)NN * HD * 4);
  __bf16* HB   = (__bf16*)alloc((size_t)NN * HD * 2);
  float*  AGG  = (float*) alloc((size_t)NN * HD * 4);
  int*    CNT  = (int*)   alloc((size_t)NN * 4);
  int*    CUR  = (int*)   alloc((size_t)NN * 4);
  int*    SRT  = (int*)   alloc((size_t)NE * 4);

  hipMemsetAsync(CNT, 0, (size_t)NN * 4, stream);
  prep_w<<<(NL * HD * 288 + 255) / 256, 256, 0, stream>>>(We1, We1t, 263, 288);
  prep_w<<<(NL * HD * 128 + 255) / 256, 256, 0, stream>>>(We2, We2t, 128, 128);
  prep_w<<<(NL * HD * 128 + 255) / 256, 256, 0, stream>>>(We3, We3t, 128, 128);
  prep_w<<<(NL * HD * 256 + 255) / 256, 256, 0, stream>>>(Wn1, Wn1t, 256, 256);
  prep_w<<<(NL * HD * 128 + 255) / 256, 256, 0, stream>>>(Wn2, Wn2t, 128, 128);
  prep_w<<<(NL * HD * 128 + 255) / 256, 256, 0, stream>>>(Wn3, Wn3t, 128, 128);
  ea_kernel<<<(NE + 255) / 256, 256, 0, stream>>>(pos, ei, EA4);
  h0_kernel<<<(NN * HD + 255) / 256, 256, 0, stream>>>(x, W_in, b_in, H32, HB);
  hist_kernel<<<(NE + 255) / 256, 256, 0, stream>>>(ei, CNT);
  scan_kernel<<<1, 1024, 0, stream>>>(CNT, CUR);
  scatter_kernel<<<(NE + 255) / 256, 256, 0, stream>>>(ei, CUR, SRT);

  for (int l = 0; l < NL; ++l) {
    hipMemsetAsync(AGG, 0, (size_t)NN * HD * 4, stream);
    edge_kernel<<<NE / EM, 256, 0, stream>>>(HB, EA4, SRT, ei,
        We1t + (size_t)l * HD * 288, We2t + (size_t)l * HD * 128,
        We3t + (size_t)l * HD * 128,
        be1 + l * HD, be2 + l * HD, be3 + l * HD, AGG);
    node_kernel<<<(NN + EM - 1) / EM, 256, 0, stream>>>(HB, AGG,
        Wn1t + (size_t)l * HD * 256, Wn2t + (size_t)l * HD * 128,
        Wn3t + (size_t)l * HD * 128,
        bn1 + l * HD, bn2 + l * HD, bn3 + l * HD,
        lng + l * HD, lnb + l * HD,
        H32, HB, (l == NL - 1) ? out : nullptr);
  }
}